// Round 7
// baseline (96.315 us; speedup 1.0000x reference)
//
#include <hip/hip_runtime.h>
#include <math.h>

#define N_WIRES 8
#define N_LAYERS 6
#define NG 49          // grid per axis (frequencies |n|<=24 -> 49 samples exact)
#define NG2 (NG * NG)  // 2401

// ws layout (bytes):
//   E  : [0, 76832)        8 x 2401 floats (grid EVs, [i][a*49+b])
//   Fb : [76832, +65536)   MFMA-B-fragment-ordered f16 F (pi folded):
//        frag fid=((i*4+ntile)*2+chunk): 64 lanes x 8 f16;
//        lane q*16+n, elem j  =  F_i[k=ntile*16+n][l=chunk*32+q*8+j]
//        (zero for k>=49 or l>=52)
#define WS_E_OFF 0
#define WS_FB_OFF 76832

typedef _Float16 half8 __attribute__((ext_vector_type(8)));
typedef float f32x4 __attribute__((ext_vector_type(4)));

// ---------------------------------------------------------------------------
// DPP-based 16-lane-row sum (pure VALU).
// ---------------------------------------------------------------------------
__device__ __forceinline__ float row16_sum(float v) {
    v += __int_as_float(__builtin_amdgcn_update_dpp(
        0, __float_as_int(v), 0xB1, 0xF, 0xF, true));   // quad_perm [1,0,3,2]
    v += __int_as_float(__builtin_amdgcn_update_dpp(
        0, __float_as_int(v), 0x4E, 0xF, 0xF, true));   // quad_perm [2,3,0,1]
    v += __int_as_float(__builtin_amdgcn_update_dpp(
        0, __float_as_int(v), 0x124, 0xF, 0xF, true));  // row_ror:4
    v += __int_as_float(__builtin_amdgcn_update_dpp(
        0, __float_as_int(v), 0x128, 0xF, 0xF, true));  // row_ror:8
    return v;
}

// ---------------------------------------------------------------------------
// CNOT-absorption mask tables. The CNOT chain is the GF(2)-linear map
// C(t)=t^(t>>1); instead of permuting data, track Phi = S^l (S = C^-1 =
// suffix-xor). During layer l (l prior CNOT layers applied):
//   partner mask  M[l][i] = C^l(e_P), P = 7-i  (bits P-k, binom(l,k) odd)
//   role bit      = parity(tid & R[l][i]),  R = row P of S^l
//                   (bits P+n: l=1 all n; l=2 n even; l=3 n%4 in {0,1};
//                    l=4 n%4==0; l=5 n%8 in {0..3})
// Final EV signs: row P of S^6 -> bits {P, P+2}.
// Spot-checked against the explicit-permutation code for layers 0-2.
// ---------------------------------------------------------------------------
static __device__ constexpr unsigned char MGATE[6][8] = {
    {0x80, 0x40, 0x20, 0x10, 0x08, 0x04, 0x02, 0x01},
    {0xC0, 0x60, 0x30, 0x18, 0x0C, 0x06, 0x03, 0x01},
    {0xA0, 0x50, 0x28, 0x14, 0x0A, 0x05, 0x02, 0x01},
    {0xF0, 0x78, 0x3C, 0x1E, 0x0F, 0x07, 0x03, 0x01},
    {0x88, 0x44, 0x22, 0x11, 0x08, 0x04, 0x02, 0x01},
    {0xCC, 0x66, 0x33, 0x19, 0x0C, 0x06, 0x03, 0x01},
};
static __device__ constexpr unsigned char RGATE[6][8] = {
    {0x80, 0x40, 0x20, 0x10, 0x08, 0x04, 0x02, 0x01},
    {0x80, 0xC0, 0xE0, 0xF0, 0xF8, 0xFC, 0xFE, 0xFF},
    {0x80, 0x40, 0xA0, 0x50, 0xA8, 0x54, 0xAA, 0x55},
    {0x80, 0xC0, 0x60, 0x30, 0x98, 0xCC, 0x66, 0x33},
    {0x80, 0x40, 0x20, 0x10, 0x88, 0x44, 0x22, 0x11},
    {0x80, 0xC0, 0xE0, 0xF0, 0x78, 0x3C, 0x1E, 0x0F},
};
static __device__ constexpr unsigned char SMASK[8] =
    {0x80, 0x40, 0xA0, 0x50, 0x28, 0x14, 0x0A, 0x05};

// ---------------------------------------------------------------------------
// Grid circuit eval, block-per-point. Round-7: CNOT stages eliminated via
// mask absorption (6 fewer barriers + LDS round-trips); gate coefficients
// read as one float4 (ds_read_b128 broadcast). Gate math values identical.
// ---------------------------------------------------------------------------
__global__ __launch_bounds__(256) void qnn_grid_lds(const float* __restrict__ w,
                                                    float* __restrict__ E) {
    __shared__ float gates[N_LAYERS * N_WIRES * 8];
    __shared__ float2 bufA[256];
    __shared__ float2 bufB[256];
    __shared__ float partial[4][8];

    const int tid = threadIdx.x;
    const int g = blockIdx.x;
    const int ga = (g * 1338) >> 16;  // g/49, exact for g < 2404
    const int gb = g - ga * NG;
    const float step = (float)(2.0 * M_PI / 49.0);

    if (tid < N_LAYERS * N_WIRES) {
        const int i = tid & 7;
        float wx = w[tid * 3 + 0], wy = w[tid * 3 + 1], wz = w[tid * 3 + 2];
        float sx, cx, sy, cy, sz, cz;
        sincosf(0.5f * wx, &sx, &cx);
        sincosf(0.5f * wy, &sy, &cy);
        sincosf(0.5f * wz, &sz, &cz);
        float A00r = cy * cx, A00i = sy * sx;
        float A01r = -sy * cx, A01i = -cy * sx;
        float A10r = sy * cx, A10i = -cy * sx;
        float A11r = cy * cx, A11i = -sy * sx;
        float U00r = A00r * cz + A00i * sz, U00i = A00i * cz - A00r * sz;
        float U01r = A01r * cz + A01i * sz, U01i = A01i * cz - A01r * sz;
        float U10r = A10r * cz - A10i * sz, U10i = A10i * cz + A10r * sz;
        float U11r = A11r * cz - A11i * sz, U11i = A11i * cz + A11r * sz;
        float V00r, V00i, V01r, V01i, V10r, V10i, V11r, V11i;
        if ((i & 1) == 0) {
            V00r = U01i; V00i = -U01r;
            V01r = U00i; V01i = -U00r;
            V10r = U11i; V10i = -U11r;
            V11r = U10i; V11i = -U10r;
        } else {
            V00r = U01r;  V00i = U01i;
            V01r = -U00r; V01i = -U00i;
            V10r = U11r;  V10i = U11i;
            V11r = -U10r; V11i = -U10i;
        }
        const float xx = (i & 1) ? (step * (float)gb) : (step * (float)ga);
        float se, ce;
        sincosf(0.5f * xx, &se, &ce);
        float* o = gates + tid * 8;
        o[0] = ce * U00r + se * V00r;  o[1] = ce * U00i + se * V00i;
        o[2] = ce * U01r + se * V01r;  o[3] = ce * U01i + se * V01i;
        o[4] = ce * U10r + se * V10r;  o[5] = ce * U10i + se * V10i;
        o[6] = ce * U11r + se * V11r;  o[7] = ce * U11i + se * V11i;
    }

    float ar = (tid == 0) ? 1.0f : 0.0f;
    float ai = 0.0f;
    __syncthreads();

    int flip = 0;
    #pragma unroll
    for (int l = 0; l < N_LAYERS; ++l) {
        // --- wires 0,1: partner mask has bit6/7 -> cross-wave, ping-pong LDS ---
        #pragma unroll
        for (int i = 0; i < 2; ++i) {
            const float* gm = gates + (l * 8 + i) * 8;
            const int m = MGATE[l][i];
            const int bit = __popc(tid & RGATE[l][i]) & 1;
            float2* buf = flip ? bufB : bufA;
            flip ^= 1;
            buf[tid] = make_float2(ar, ai);
            __syncthreads();
            float2 other = buf[tid ^ m];
            float a0r = bit ? other.x : ar, a0i = bit ? other.y : ai;
            float a1r = bit ? ar : other.x, a1i = bit ? ai : other.y;
            float4 cc = *(const float4*)(gm + bit * 4);
            float nr = cc.x * a0r - cc.y * a0i + cc.z * a1r - cc.w * a1i;
            float ni = cc.x * a0i + cc.y * a0r + cc.z * a1i + cc.w * a1r;
            ar = nr; ai = ni;
        }
        // --- wires 2..7: composite masks <= 0x3F -> intra-wave shfl_xor ---
        #pragma unroll
        for (int i = 2; i < 8; ++i) {
            const float* gm = gates + (l * 8 + i) * 8;
            const int m = MGATE[l][i];
            const int bit = __popc(tid & RGATE[l][i]) & 1;
            float otr = __shfl_xor(ar, m);
            float oti = __shfl_xor(ai, m);
            float a0r = bit ? otr : ar, a0i = bit ? oti : ai;
            float a1r = bit ? ar : otr, a1i = bit ? ai : oti;
            float4 cc = *(const float4*)(gm + bit * 4);
            float nr = cc.x * a0r - cc.y * a0i + cc.z * a1r - cc.w * a1i;
            float ni = cc.x * a0i + cc.y * a0r + cc.z * a1i + cc.w * a1r;
            ar = nr; ai = ni;
        }
        // CNOT chain: absorbed into masks -- no data movement.
    }

    float p = ar * ar + ai * ai;
    float ev[8];
    #pragma unroll
    for (int i = 0; i < 8; ++i)
        ev[i] = (__popc(tid & SMASK[i]) & 1) ? -p : p;
    #pragma unroll
    for (int i = 0; i < 8; ++i) {
        float v = row16_sum(ev[i]);
        v += __shfl_xor(v, 16);
        v += __shfl_xor(v, 32);
        ev[i] = v;
    }
    const int wave = tid >> 6, lane = tid & 63;
    if (lane == 0) {
        #pragma unroll
        for (int i = 0; i < 8; ++i) partial[wave][i] = ev[i];
    }
    __syncthreads();
    if (tid < 8) {
        E[tid * NG2 + g] = partial[0][tid] + partial[1][tid] + partial[2][tid] + partial[3][tid];
    }
}

// ---------------------------------------------------------------------------
// Fused separable 2D DFT. Round-7: was 512 one-wave blocks (0.5 waves/SIMD)
// with 49-deep serial FMA chains; now 256-thread blocks where 4 waves split
// each 49-term sum into 13-term partials (4x shorter chains, 4x resident
// waves), combined in fixed order via LDS. Same basis table and I/O mapping.
// ---------------------------------------------------------------------------
__global__ __launch_bounds__(256) void dft2(const float* __restrict__ E,
                                            _Float16* __restrict__ Fb) {
    const int kp = blockIdx.x, i = blockIdx.y;
    const int t = threadIdx.x, w = t >> 6, lane = t & 63;
    __shared__ float Es[NG2];
    __shared__ float tc[NG], ts[NG];
    __shared__ float Hp[4][NG + 3];
    __shared__ float H[NG];
    __shared__ float Fp[4][64];
    const float step = (float)(2.0 * M_PI / 49.0);
    const float PI = 3.14159265358979323846f;

    if (t < NG) {
        float s, c;
        sincosf(step * (float)t, &s, &c);
        tc[t] = c; ts[t] = s;
    }
    for (int e = t; e < NG2; e += 256) Es[e] = E[i * NG2 + e];
    __syncthreads();

    // stage 1 partials: b = lane, wave w covers a in [13w, min(13w+13,49))
    if (kp < NG && lane < NG) {
        const int a0 = w * 13, a1 = (a0 + 13 < NG) ? a0 + 13 : NG;
        const int n = (kp + 1) >> 1;  // 0 for kp==0
        const bool use_cos = (kp & 1) || (kp == 0);
        float acc = 0.f;
        int j = (a0 * n) % NG;
        for (int a = a0; a < a1; ++a) {
            acc = fmaf(Es[a * NG + lane], use_cos ? tc[j] : ts[j], acc);
            j += n; if (j >= NG) j -= NG;
        }
        Hp[w][lane] = acc;
    }
    __syncthreads();

    if (t < NG) {
        float h = ((Hp[0][t] + Hp[1][t]) + Hp[2][t]) + Hp[3][t];
        h *= (kp == 0) ? (1.0f / 49.0f) : (2.0f / 49.0f);
        H[t] = h;
    }
    __syncthreads();

    // stage 2 partials: l = lane, wave w covers b in [13w, min(13w+13,49))
    {
        float acc = 0.f;
        if (kp < NG && lane < NG) {
            const int b0 = w * 13, b1 = (b0 + 13 < NG) ? b0 + 13 : NG;
            const int n = (lane + 1) >> 1;  // 0 for lane==0
            const bool use_cos = (lane & 1) || (lane == 0);
            int j = (b0 * n) % NG;
            for (int b = b0; b < b1; ++b) {
                acc = fmaf(H[b], use_cos ? tc[j] : ts[j], acc);
                j += n; if (j >= NG) j -= NG;
            }
        }
        Fp[w][lane] = acc;
    }
    __syncthreads();

    if (t < 64) {
        const int l = t;
        float acc = ((Fp[0][l] + Fp[1][l]) + Fp[2][l]) + Fp[3][l];
        acc *= (l == 0) ? (PI / 49.0f) : (2.0f * PI / 49.0f);
        if (kp >= NG || l >= NG) acc = 0.f;
        const int ntile = kp >> 4, n = kp & 15;
        const int chunk = l >> 5, lrem = l & 31;
        const int q = lrem >> 3, j = lrem & 7;
        const int fid = (i * 4 + ntile) * 2 + chunk;
        Fb[fid * 512 + (q * 16 + n) * 8 + j] = (_Float16)acc;
    }
}

// ---------------------------------------------------------------------------
// MFMA contraction (round-6 structure). FROZEN.
// ---------------------------------------------------------------------------
#define V0PAD 68

__global__ __launch_bounds__(256, 4) void contract_mfma(const float* __restrict__ x,
                                                        const _Float16* __restrict__ Fb,
                                                        float* __restrict__ out, int B) {
    __shared__ float xs0[64], xs1[64];
    __shared__ float v0t[64 * V0PAD];              // 17.4 KB
    __shared__ __align__(16) half8 aS[2 * 4 * 64]; // 8 KB: [c][bg][lane]

    const int tid = threadIdx.x;
    const int bbase = blockIdx.x * 64;
    if (bbase >= B) return;

    const int lane = tid & 63;
    const int w = tid >> 6;
    const int q = lane >> 4;

    const half8* FB = (const half8*)Fb;
    half8 bfrag[16];
    #pragma unroll
    for (int f = 0; f < 16; ++f) bfrag[f] = FB[(w * 16 + f) * 64 + lane];

    if (tid < 64) {
        float2 xv = ((const float2*)x)[bbase + tid];
        xs0[tid] = xv.x;
        xs1[tid] = xv.y;
    }
    __syncthreads();

    {
        const int b = tid & 63, s = tid >> 6;
        const float x0 = xs0[b];
        float c1, s1;
        sincosf(x0, &s1, &c1);
        float s2v = 2.f * s1 * c1, c2v = 1.f - 2.f * s1 * s1;
        float s4v = 2.f * s2v * c2v, c4v = 1.f - 2.f * s2v * s2v;
        float s8v = 2.f * s4v * c4v, c8v = 1.f - 2.f * s4v * s4v;
        float sb, cb;
        if (s == 0) {
            sb = 0.f; cb = 1.f;
        } else if (s == 1) {
            sb = s8v; cb = c8v;
        } else if (s == 2) {
            sb = 2.f * s8v * c8v; cb = 1.f - 2.f * s8v * s8v;
        } else {
            float s16v = 2.f * s8v * c8v, c16v = 1.f - 2.f * s8v * s8v;
            sb = s16v * c8v + c16v * s8v; cb = c16v * c8v - s16v * s8v;
        }
        float* row = v0t + b * V0PAD + 16 * s;
        const int k0 = 16 * s;
        row[0] = (k0 == 0) ? 1.0f : ((k0 < NG) ? sb : 0.0f);
        float cm = cb, sm = sb;
        #pragma unroll
        for (int j = 1; j < 16; ++j) {
            if (j & 1) {
                float c2 = cm * c1 - sm * s1, s2 = sm * c1 + cm * s1;
                cm = c2; sm = s2;
            }
            float val = (j & 1) ? cm : sm;
            row[j] = ((k0 + j) < NG) ? val : 0.0f;
        }
    }

    {
        const float x1v = xs1[w * 16 + (lane & 15)];
        float c1, s1;
        sincosf(x1v, &s1, &c1);
        float s2v = 2.f * s1 * c1, c2v = 1.f - 2.f * s1 * s1;
        float s4v = 2.f * s2v * c2v, c4v = 1.f - 2.f * s2v * s2v;
        float s8v = 2.f * s4v * c4v, c8v = 1.f - 2.f * s4v * s4v;
        float s12v = s8v * c4v + c8v * s4v, c12v = c8v * c4v - s8v * s4v;
        float sq = (q == 0) ? 0.f : ((q == 1) ? s4v : ((q == 2) ? s8v : s12v));
        float cq = (q == 0) ? 1.f : ((q == 1) ? c4v : ((q == 2) ? c8v : c12v));
        float s16v = 2.f * s8v * c8v, c16v = 1.f - 2.f * s8v * s8v;
        float sb_c[2], cb_c[2];
        sb_c[0] = sq;                      cb_c[0] = cq;
        sb_c[1] = sq * c16v + cq * s16v;   cb_c[1] = cq * c16v - sq * s16v;
        #pragma unroll
        for (int c = 0; c < 2; ++c) {
            const int l0 = c * 32 + q * 8;
            float cb = cb_c[c], sb = sb_c[c];
            float vals[8];
            vals[0] = (l0 == 0) ? 1.0f : sb;
            float cm = cb, sm = sb;
            #pragma unroll
            for (int j = 1; j < 8; ++j) {
                if (j & 1) {
                    float c2 = cm * c1 - sm * s1, s2 = sm * c1 + cm * s1;
                    cm = c2; sm = s2;
                }
                vals[j] = (j & 1) ? cm : sm;
            }
            half8 af;
            #pragma unroll
            for (int j = 0; j < 8; ++j) {
                af[j] = (_Float16)(((l0 + j) < 52) ? vals[j] : 0.0f);
            }
            aS[(c * 4 + w) * 64 + lane] = af;
        }
    }

    __syncthreads();

    #pragma unroll 1
    for (int bg = 0; bg < 4; ++bg) {
        const half8 a0 = aS[(0 * 4 + bg) * 64 + lane];
        const half8 a1 = aS[(1 * 4 + bg) * 64 + lane];

        float res[2][4];
        #pragma unroll
        for (int ii = 0; ii < 2; ++ii)
            #pragma unroll
            for (int r = 0; r < 4; ++r) res[ii][r] = 0.f;

        #pragma unroll
        for (int nt = 0; nt < 4; ++nt) {
            float v0[4];
            #pragma unroll
            for (int r = 0; r < 4; ++r)
                v0[r] = v0t[(bg * 16 + q * 4 + r) * V0PAD + nt * 16 + (lane & 15)];

            f32x4 z = {0.f, 0.f, 0.f, 0.f};
            f32x4 acc0 = __builtin_amdgcn_mfma_f32_16x16x32_f16(a0, bfrag[nt * 2 + 0], z, 0, 0, 0);
            acc0 = __builtin_amdgcn_mfma_f32_16x16x32_f16(a1, bfrag[nt * 2 + 1], acc0, 0, 0, 0);
            f32x4 acc1 = __builtin_amdgcn_mfma_f32_16x16x32_f16(a0, bfrag[(4 + nt) * 2 + 0], z, 0, 0, 0);
            acc1 = __builtin_amdgcn_mfma_f32_16x16x32_f16(a1, bfrag[(4 + nt) * 2 + 1], acc1, 0, 0, 0);

            #pragma unroll
            for (int r = 0; r < 4; ++r) {
                res[0][r] = fmaf(acc0[r], v0[r], res[0][r]);
                res[1][r] = fmaf(acc1[r], v0[r], res[1][r]);
            }
        }

        #pragma unroll
        for (int ii = 0; ii < 2; ++ii)
            #pragma unroll
            for (int r = 0; r < 4; ++r) {
                res[ii][r] = row16_sum(res[ii][r]);
            }

        if ((lane & 15) == 0) {
            #pragma unroll
            for (int r = 0; r < 4; ++r) {
                const int b = bbase + bg * 16 + q * 4 + r;
                float2 st = make_float2(res[0][r], res[1][r]);
                *(float2*)&out[(size_t)b * 8 + 2 * w] = st;
            }
        }
    }
}

extern "C" void kernel_launch(void* const* d_in, const int* in_sizes, int n_in,
                              void* d_out, int out_size, void* d_ws, size_t ws_size,
                              hipStream_t stream) {
    (void)n_in; (void)out_size; (void)ws_size;
    const float* x = (const float*)d_in[0];
    const float* w = (const float*)d_in[1];
    float* out = (float*)d_out;
    char* ws = (char*)d_ws;
    float* E = (float*)(ws + WS_E_OFF);
    _Float16* Fb = (_Float16*)(ws + WS_FB_OFF);
    const int B = in_sizes[0] / 2;

    hipLaunchKernelGGL(qnn_grid_lds, dim3(NG2), dim3(256), 0, stream, w, E);
    hipLaunchKernelGGL(dft2, dim3(64, 8), dim3(256), 0, stream, E, Fb);
    hipLaunchKernelGGL(contract_mfma, dim3((B + 63) / 64, 1), dim3(256), 0, stream,
                       x, Fb, out, B);
}

// Round 12
// 96.157 us; speedup vs baseline: 1.0016x; 1.0016x over previous
//
#include <hip/hip_runtime.h>
#include <math.h>

#define N_WIRES 8
#define N_LAYERS 6
#define NG 49          // grid per axis (frequencies |n|<=24 -> 49 samples exact)
#define NG2 (NG * NG)  // 2401

// ws layout (bytes):
//   E  : [0, 76832)        8 x 2401 floats (grid EVs, [i][a*49+b])
//   Fb : [76832, +65536)   MFMA-B-fragment-ordered f16 F (pi folded):
//        frag fid=((i*4+ntile)*2+chunk): 64 lanes x 8 f16;
//        lane q*16+n, elem j  =  F_i[k=ntile*16+n][l=chunk*32+q*8+j]
//        (zero for k>=49 or l>=52)
#define WS_E_OFF 0
#define WS_FB_OFF 76832

typedef _Float16 half8 __attribute__((ext_vector_type(8)));
typedef float f32x4 __attribute__((ext_vector_type(4)));

// ---------------------------------------------------------------------------
// DPP-based 16-lane-row sum: quad_perm xor1/xor2 then row_ror 4/8.
// Pure VALU (v_add_f32_dpp). Every lane ends with the full 16-lane sum.
// ---------------------------------------------------------------------------
__device__ __forceinline__ float row16_sum(float v) {
    v += __int_as_float(__builtin_amdgcn_update_dpp(
        0, __float_as_int(v), 0xB1, 0xF, 0xF, true));   // quad_perm [1,0,3,2]
    v += __int_as_float(__builtin_amdgcn_update_dpp(
        0, __float_as_int(v), 0x4E, 0xF, 0xF, true));   // quad_perm [2,3,0,1]
    v += __int_as_float(__builtin_amdgcn_update_dpp(
        0, __float_as_int(v), 0x124, 0xF, 0xF, true));  // row_ror:4
    v += __int_as_float(__builtin_amdgcn_update_dpp(
        0, __float_as_int(v), 0x128, 0xF, 0xF, true));  // row_ror:8
    return v;
}

// ---------------------------------------------------------------------------
// Grid circuit eval, block-per-point (round-5 structure). FROZEN.
// ---------------------------------------------------------------------------
__global__ __launch_bounds__(256) void qnn_grid_lds(const float* __restrict__ w,
                                                    float* __restrict__ E) {
    __shared__ float gates[N_LAYERS * N_WIRES * 8];
    __shared__ float2 bufA[256];
    __shared__ float2 bufB[256];
    __shared__ float partial[4][8];

    const int tid = threadIdx.x;
    const int g = blockIdx.x;
    const int ga = (g * 1338) >> 16;  // g/49, exact for g < 2404
    const int gb = g - ga * NG;
    const float step = (float)(2.0 * M_PI / 49.0);

    if (tid < N_LAYERS * N_WIRES) {
        const int i = tid & 7;
        float wx = w[tid * 3 + 0], wy = w[tid * 3 + 1], wz = w[tid * 3 + 2];
        float sx, cx, sy, cy, sz, cz;
        sincosf(0.5f * wx, &sx, &cx);
        sincosf(0.5f * wy, &sy, &cy);
        sincosf(0.5f * wz, &sz, &cz);
        float A00r = cy * cx, A00i = sy * sx;
        float A01r = -sy * cx, A01i = -cy * sx;
        float A10r = sy * cx, A10i = -cy * sx;
        float A11r = cy * cx, A11i = -sy * sx;
        float U00r = A00r * cz + A00i * sz, U00i = A00i * cz - A00r * sz;
        float U01r = A01r * cz + A01i * sz, U01i = A01i * cz - A01r * sz;
        float U10r = A10r * cz - A10i * sz, U10i = A10i * cz + A10r * sz;
        float U11r = A11r * cz - A11i * sz, U11i = A11i * cz + A11r * sz;
        float V00r, V00i, V01r, V01i, V10r, V10i, V11r, V11i;
        if ((i & 1) == 0) {
            V00r = U01i; V00i = -U01r;
            V01r = U00i; V01i = -U00r;
            V10r = U11i; V10i = -U11r;
            V11r = U10i; V11i = -U10r;
        } else {
            V00r = U01r;  V00i = U01i;
            V01r = -U00r; V01i = -U00i;
            V10r = U11r;  V10i = U11i;
            V11r = -U10r; V11i = -U10i;
        }
        const float xx = (i & 1) ? (step * (float)gb) : (step * (float)ga);
        float se, ce;
        sincosf(0.5f * xx, &se, &ce);
        float* o = gates + tid * 8;
        o[0] = ce * U00r + se * V00r;  o[1] = ce * U00i + se * V00i;
        o[2] = ce * U01r + se * V01r;  o[3] = ce * U01i + se * V01i;
        o[4] = ce * U10r + se * V10r;  o[5] = ce * U10i + se * V10i;
        o[6] = ce * U11r + se * V11r;  o[7] = ce * U11i + se * V11i;
    }

    float ar = (tid == 0) ? 1.0f : 0.0f;
    float ai = 0.0f;
    __syncthreads();

    int flip = 0;
    for (int l = 0; l < N_LAYERS; ++l) {
        #pragma unroll
        for (int i = 0; i < 2; ++i) {
            const float* gm = gates + (l * 8 + i) * 8;
            const int p = 7 - i;
            const int m = 1 << p;
            const int bit = (tid >> p) & 1;
            float2* buf = flip ? bufB : bufA;
            flip ^= 1;
            buf[tid] = make_float2(ar, ai);
            __syncthreads();
            float2 other = buf[tid ^ m];
            float a0r = bit ? other.x : ar, a0i = bit ? other.y : ai;
            float a1r = bit ? ar : other.x, a1i = bit ? ai : other.y;
            float c0r = gm[bit * 4 + 0], c0i = gm[bit * 4 + 1];
            float c1r = gm[bit * 4 + 2], c1i = gm[bit * 4 + 3];
            float nr = c0r * a0r - c0i * a0i + c1r * a1r - c1i * a1i;
            float ni = c0r * a0i + c0i * a0r + c1r * a1i + c1i * a1r;
            ar = nr; ai = ni;
        }
        #pragma unroll
        for (int i = 2; i < 8; ++i) {
            const float* gm = gates + (l * 8 + i) * 8;
            const int p = 7 - i;
            const int m = 1 << p;
            const int bit = (tid >> p) & 1;
            float otr = __shfl_xor(ar, m);
            float oti = __shfl_xor(ai, m);
            float a0r = bit ? otr : ar, a0i = bit ? oti : ai;
            float a1r = bit ? ar : otr, a1i = bit ? ai : oti;
            float c0r = gm[bit * 4 + 0], c0i = gm[bit * 4 + 1];
            float c1r = gm[bit * 4 + 2], c1i = gm[bit * 4 + 3];
            float nr = c0r * a0r - c0i * a0i + c1r * a1r - c1i * a1i;
            float ni = c0r * a0i + c0i * a0r + c1r * a1i + c1i * a1r;
            ar = nr; ai = ni;
        }
        {
            float2* buf = flip ? bufB : bufA;
            flip ^= 1;
            buf[tid] = make_float2(ar, ai);
            __syncthreads();
            float2 src = buf[tid ^ (tid >> 1)];
            ar = src.x; ai = src.y;
        }
    }

    float p = ar * ar + ai * ai;
    float ev[8];
    #pragma unroll
    for (int i = 0; i < 8; ++i) ev[i] = ((tid >> (7 - i)) & 1) ? -p : p;
    #pragma unroll
    for (int i = 0; i < 8; ++i) {
        float v = row16_sum(ev[i]);
        v += __shfl_xor(v, 16);
        v += __shfl_xor(v, 32);
        ev[i] = v;
    }
    const int wave = tid >> 6, lane = tid & 63;
    if (lane == 0) {
        #pragma unroll
        for (int i = 0; i < 8; ++i) partial[wave][i] = ev[i];
    }
    __syncthreads();
    if (tid < 8) {
        E[tid * NG2 + g] = partial[0][tid] + partial[1][tid] + partial[2][tid] + partial[3][tid];
    }
}

// ---------------------------------------------------------------------------
// Fused separable 2D DFT (exact mod-49 table). FROZEN.
// ---------------------------------------------------------------------------
__global__ __launch_bounds__(64) void dft2(const float* __restrict__ E,
                                           _Float16* __restrict__ Fb) {
    const int kp = blockIdx.x, i = blockIdx.y, t = threadIdx.x;
    __shared__ float Es[NG2];
    __shared__ float H[NG];
    __shared__ float tc[NG], ts[NG];
    const float step = (float)(2.0 * M_PI / 49.0);
    const float PI = 3.14159265358979323846f;

    if (t < NG) {
        float s, c;
        sincosf(step * (float)t, &s, &c);
        tc[t] = c; ts[t] = s;
    }
    if (kp < NG) {
        for (int e = t; e < NG2; e += 64) Es[e] = E[i * NG2 + e];
    }
    __syncthreads();

    if (kp < NG && t < NG) {
        const int b = t;
        const int n = (kp + 1) >> 1;  // 0 for kp==0
        const bool use_cos = (kp & 1) || (kp == 0);
        float acc = 0.f;
        int j = 0;
        for (int a = 0; a < NG; ++a) {
            acc = fmaf(Es[a * NG + b], use_cos ? tc[j] : ts[j], acc);
            j += n; if (j >= NG) j -= NG;
        }
        acc *= (kp == 0) ? (1.0f / 49.0f) : (2.0f / 49.0f);
        H[b] = acc;
    }
    __syncthreads();

    const int l = t;
    float acc = 0.f;
    if (kp < NG && l < NG) {
        const int n = (l + 1) >> 1;  // 0 for l==0
        const bool use_cos = (l & 1) || (l == 0);
        int j = 0;
        for (int b = 0; b < NG; ++b) {
            acc = fmaf(H[b], use_cos ? tc[j] : ts[j], acc);
            j += n; if (j >= NG) j -= NG;
        }
        acc *= (l == 0) ? (PI / 49.0f) : (2.0f * PI / 49.0f);
    }
    {
        const int ntile = kp >> 4, n = kp & 15;
        const int chunk = l >> 5, lrem = l & 31;
        const int q = lrem >> 3, j = lrem & 7;
        const int fid = (i * 4 + ntile) * 2 + chunk;
        Fb[fid * 512 + (q * 16 + n) * 8 + j] = (_Float16)acc;
    }
}

// ---------------------------------------------------------------------------
// MFMA contraction, round-6 structure: wave w owns i-pair w, resident
// B-frags, A via LDS, no main-loop barriers; MFMA and epilogue-FMA
// interleaved per nt (2 accs in flight), __launch_bounds__(256,4).
// ---------------------------------------------------------------------------
#define V0PAD 68

__global__ __launch_bounds__(256, 4) void contract_mfma(const float* __restrict__ x,
                                                        const _Float16* __restrict__ Fb,
                                                        float* __restrict__ out, int B) {
    __shared__ float xs0[64], xs1[64];
    __shared__ float v0t[64 * V0PAD];              // 17.4 KB
    __shared__ __align__(16) half8 aS[2 * 4 * 64]; // 8 KB: [c][bg][lane]

    const int tid = threadIdx.x;
    const int bbase = blockIdx.x * 64;
    if (bbase >= B) return;

    const int lane = tid & 63;
    const int w = tid >> 6;
    const int q = lane >> 4;

    // ---- issue this wave's 16 resident B-fragment loads NOW; latency
    //      hides under the build phase below ----
    const half8* FB = (const half8*)Fb;
    half8 bfrag[16];
    #pragma unroll
    for (int f = 0; f < 16; ++f) bfrag[f] = FB[(w * 16 + f) * 64 + lane];

    if (tid < 64) {
        float2 xv = ((const float2*)x)[bbase + tid];
        xs0[tid] = xv.x;
        xs1[tid] = xv.y;
    }
    __syncthreads();

    // ---- v0 table: thread t -> batch b=t&63, k-segment s=t>>6 (16 k's) ----
    {
        const int b = tid & 63, s = tid >> 6;
        const float x0 = xs0[b];
        float c1, s1;
        sincosf(x0, &s1, &c1);
        float s2v = 2.f * s1 * c1, c2v = 1.f - 2.f * s1 * s1;
        float s4v = 2.f * s2v * c2v, c4v = 1.f - 2.f * s2v * s2v;
        float s8v = 2.f * s4v * c4v, c8v = 1.f - 2.f * s4v * s4v;
        float sb, cb;
        if (s == 0) {            // wave-uniform branch (s = tid>>6)
            sb = 0.f; cb = 1.f;
        } else if (s == 1) {
            sb = s8v; cb = c8v;
        } else if (s == 2) {
            sb = 2.f * s8v * c8v; cb = 1.f - 2.f * s8v * s8v;
        } else {
            float s16v = 2.f * s8v * c8v, c16v = 1.f - 2.f * s8v * s8v;
            sb = s16v * c8v + c16v * s8v; cb = c16v * c8v - s16v * s8v;
        }
        float* row = v0t + b * V0PAD + 16 * s;
        const int k0 = 16 * s;
        row[0] = (k0 == 0) ? 1.0f : ((k0 < NG) ? sb : 0.0f);
        float cm = cb, sm = sb;
        #pragma unroll
        for (int j = 1; j < 16; ++j) {
            if (j & 1) {
                float c2 = cm * c1 - sm * s1, s2 = sm * c1 + cm * s1;
                cm = c2; sm = s2;
            }
            float val = (j & 1) ? cm : sm;
            row[j] = ((k0 + j) < NG) ? val : 0.0f;
        }
    }

    // ---- A fragments for THIS thread's batch, staged to LDS ----
    {
        const float x1v = xs1[w * 16 + (lane & 15)];
        float c1, s1;
        sincosf(x1v, &s1, &c1);
        float s2v = 2.f * s1 * c1, c2v = 1.f - 2.f * s1 * s1;
        float s4v = 2.f * s2v * c2v, c4v = 1.f - 2.f * s2v * s2v;
        float s8v = 2.f * s4v * c4v, c8v = 1.f - 2.f * s4v * s4v;
        float s12v = s8v * c4v + c8v * s4v, c12v = c8v * c4v - s8v * s4v;
        float sq = (q == 0) ? 0.f : ((q == 1) ? s4v : ((q == 2) ? s8v : s12v));
        float cq = (q == 0) ? 1.f : ((q == 1) ? c4v : ((q == 2) ? c8v : c12v));
        float s16v = 2.f * s8v * c8v, c16v = 1.f - 2.f * s8v * s8v;
        float sb_c[2], cb_c[2];
        sb_c[0] = sq;                      cb_c[0] = cq;
        sb_c[1] = sq * c16v + cq * s16v;   cb_c[1] = cq * c16v - sq * s16v;
        #pragma unroll
        for (int c = 0; c < 2; ++c) {
            const int l0 = c * 32 + q * 8;
            float cb = cb_c[c], sb = sb_c[c];
            float vals[8];
            vals[0] = (l0 == 0) ? 1.0f : sb;
            float cm = cb, sm = sb;
            #pragma unroll
            for (int j = 1; j < 8; ++j) {
                if (j & 1) {
                    float c2 = cm * c1 - sm * s1, s2 = sm * c1 + cm * s1;
                    cm = c2; sm = s2;
                }
                vals[j] = (j & 1) ? cm : sm;
            }
            half8 af;
            #pragma unroll
            for (int j = 0; j < 8; ++j) {
                af[j] = (_Float16)(((l0 + j) < 52) ? vals[j] : 0.0f);
            }
            aS[(c * 4 + w) * 64 + lane] = af;
        }
    }

    __syncthreads();  // v0t + aS ready; bfrag loads drained by barrier's vmcnt(0)

    // ---- main loop: wave w = i-pair w, iterate batch-groups. NO barriers.
    //      MFMA and epilogue FMA interleaved per nt: only 2 accs live. ----
    #pragma unroll 1
    for (int bg = 0; bg < 4; ++bg) {
        const half8 a0 = aS[(0 * 4 + bg) * 64 + lane];
        const half8 a1 = aS[(1 * 4 + bg) * 64 + lane];

        float res[2][4];
        #pragma unroll
        for (int ii = 0; ii < 2; ++ii)
            #pragma unroll
            for (int r = 0; r < 4; ++r) res[ii][r] = 0.f;

        #pragma unroll
        for (int nt = 0; nt < 4; ++nt) {
            float v0[4];
            #pragma unroll
            for (int r = 0; r < 4; ++r)
                v0[r] = v0t[(bg * 16 + q * 4 + r) * V0PAD + nt * 16 + (lane & 15)];

            f32x4 z = {0.f, 0.f, 0.f, 0.f};
            f32x4 acc0 = __builtin_amdgcn_mfma_f32_16x16x32_f16(a0, bfrag[nt * 2 + 0], z, 0, 0, 0);
            acc0 = __builtin_amdgcn_mfma_f32_16x16x32_f16(a1, bfrag[nt * 2 + 1], acc0, 0, 0, 0);
            f32x4 acc1 = __builtin_amdgcn_mfma_f32_16x16x32_f16(a0, bfrag[(4 + nt) * 2 + 0], z, 0, 0, 0);
            acc1 = __builtin_amdgcn_mfma_f32_16x16x32_f16(a1, bfrag[(4 + nt) * 2 + 1], acc1, 0, 0, 0);

            #pragma unroll
            for (int r = 0; r < 4; ++r) {
                res[0][r] = fmaf(acc0[r], v0[r], res[0][r]);
                res[1][r] = fmaf(acc1[r], v0[r], res[1][r]);
            }
        }

        #pragma unroll
        for (int ii = 0; ii < 2; ++ii)
            #pragma unroll
            for (int r = 0; r < 4; ++r) {
                res[ii][r] = row16_sum(res[ii][r]);  // DPP, no LDS pipe
            }

        if ((lane & 15) == 0) {
            #pragma unroll
            for (int r = 0; r < 4; ++r) {
                const int b = bbase + bg * 16 + q * 4 + r;
                float2 st = make_float2(res[0][r], res[1][r]);
                *(float2*)&out[(size_t)b * 8 + 2 * w] = st;
            }
        }
    }
}

extern "C" void kernel_launch(void* const* d_in, const int* in_sizes, int n_in,
                              void* d_out, int out_size, void* d_ws, size_t ws_size,
                              hipStream_t stream) {
    (void)n_in; (void)out_size; (void)ws_size;
    const float* x = (const float*)d_in[0];
    const float* w = (const float*)d_in[1];
    float* out = (float*)d_out;
    char* ws = (char*)d_ws;
    float* E = (float*)(ws + WS_E_OFF);
    _Float16* Fb = (_Float16*)(ws + WS_FB_OFF);
    const int B = in_sizes[0] / 2;

    hipLaunchKernelGGL(qnn_grid_lds, dim3(NG2), dim3(256), 0, stream, w, E);
    hipLaunchKernelGGL(dft2, dim3(64, 8), dim3(64), 0, stream, E, Fb);
    hipLaunchKernelGGL(contract_mfma, dim3((B + 63) / 64, 1), dim3(256), 0, stream,
                       x, Fb, out, B);
}